// Round 1
// baseline (312.743 us; speedup 1.0000x reference)
//
#include <hip/hip_runtime.h>
#include <hip/hip_bf16.h>
#include <stdint.h>

// out[b,s,o] = sum_d x[b,s,d] * expert_w[0][o,d] + expert_b[0][o]
// => C(MxN) = A(MxK) * B(NxK)^T + bias, M=8192, N=2048, K=2048, fp32 I/O.
// Pass 1: convert x and W0 fp32 -> bf16 into d_ws.
// Pass 2: m97-structure bf16 MFMA GEMM (128x128 tile, BK=32, global_load_lds).

#define M_DIM 8192
#define N_DIM 2048
#define K_DIM 2048
#define BM 128
#define BN 128
#define BK 32

typedef __attribute__((ext_vector_type(8))) short bf16x8;
typedef __attribute__((ext_vector_type(4))) float f32x4;

__device__ __forceinline__ unsigned short f2bf(float f) {
    union { float f; uint32_t u; } v; v.f = f;
    uint32_t u = v.u;
    // round-to-nearest-even
    uint32_t r = (u + 0x7fffu + ((u >> 16) & 1u)) >> 16;
    return (unsigned short)r;
}

__global__ __launch_bounds__(256) void cvt_f32_to_bf16(
        const float* __restrict__ x, const float* __restrict__ w,
        unsigned short* __restrict__ xb, unsigned short* __restrict__ wb,
        int nx4, int nw4) {
    const int stride = gridDim.x * blockDim.x;
    const int i0 = blockIdx.x * blockDim.x + threadIdx.x;
    for (int i = i0; i < nx4; i += stride) {
        float4 v = ((const float4*)x)[i];
        ushort4 o;
        o.x = f2bf(v.x); o.y = f2bf(v.y); o.z = f2bf(v.z); o.w = f2bf(v.w);
        ((ushort4*)xb)[i] = o;
    }
    for (int i = i0; i < nw4; i += stride) {
        float4 v = ((const float4*)w)[i];
        ushort4 o;
        o.x = f2bf(v.x); o.y = f2bf(v.y); o.z = f2bf(v.z); o.w = f2bf(v.w);
        ((ushort4*)wb)[i] = o;
    }
}

__global__ __launch_bounds__(256) void gemm_bt_bias(
        const unsigned short* __restrict__ A,   // M x K bf16 (x)
        const unsigned short* __restrict__ B,   // N x K bf16 (W0, row-major o,d)
        const float* __restrict__ bias,         // N fp32 (expert_b[0])
        float* __restrict__ C) {                // M x N fp32
    __shared__ unsigned short As[BM * BK];
    __shared__ unsigned short Bs[BN * BK];

    const int t    = threadIdx.x;
    const int lane = t & 63;
    const int wv   = t >> 6;      // 0..3
    const int wm   = wv >> 1;     // 0..1 (M half)
    const int wn   = wv & 1;      // 0..1 (N half)

    const int bid = blockIdx.x;   // 1024 blocks
    const int bm  = bid >> 4;     // 0..63
    const int bn  = bid & 15;     // 0..15

    const int row16 = lane & 15;
    const int kb    = (lane >> 4) << 3;    // 0,8,16,24 (fragment k base)

    // staging lane decomposition: 4 lanes per 64B row segment
    const int srow = lane >> 2;            // 0..15 row within 16-row chunk
    const int scol = (lane & 3) << 3;      // element col offset 0,8,16,24

    f32x4 acc[4][4];
#pragma unroll
    for (int i = 0; i < 4; ++i)
#pragma unroll
        for (int j = 0; j < 4; ++j)
            acc[i][j] = (f32x4){0.f, 0.f, 0.f, 0.f};

    const size_t a_base = (size_t)(bm * BM) * K_DIM;
    const size_t b_base = (size_t)(bn * BN) * K_DIM;

    for (int k0 = 0; k0 < K_DIM; k0 += BK) {
        // --- stage A and B tiles via async global->LDS (16B/lane) ---
#pragma unroll
        for (int r = 0; r < 2; ++r) {
            const int chunk = wv * 2 + r;               // 0..7 (16-row chunk)
            const unsigned short* ga =
                A + a_base + (size_t)(chunk * 16 + srow) * K_DIM + k0 + scol;
            __builtin_amdgcn_global_load_lds(
                (const __attribute__((address_space(1))) void*)ga,
                (__attribute__((address_space(3))) void*)&As[chunk * 16 * BK],
                16, 0, 0);
            const unsigned short* gb =
                B + b_base + (size_t)(chunk * 16 + srow) * K_DIM + k0 + scol;
            __builtin_amdgcn_global_load_lds(
                (const __attribute__((address_space(1))) void*)gb,
                (__attribute__((address_space(3))) void*)&Bs[chunk * 16 * BK],
                16, 0, 0);
        }
        __syncthreads();   // compiler drains vmcnt before s_barrier

        // --- fragments + MFMA ---
        bf16x8 af[4], bq[4];
#pragma unroll
        for (int mi = 0; mi < 4; ++mi)
            af[mi] = *(const bf16x8*)&As[(wm * 64 + mi * 16 + row16) * BK + kb];
#pragma unroll
        for (int ni = 0; ni < 4; ++ni)
            bq[ni] = *(const bf16x8*)&Bs[(wn * 64 + ni * 16 + row16) * BK + kb];

#pragma unroll
        for (int mi = 0; mi < 4; ++mi)
#pragma unroll
            for (int ni = 0; ni < 4; ++ni)
                acc[mi][ni] = __builtin_amdgcn_mfma_f32_16x16x32_bf16(
                    af[mi], bq[ni], acc[mi][ni], 0, 0, 0);

        __syncthreads();   // all reads done before next-tile overwrite
    }

    // --- epilogue: bias + store (C/D layout: col=lane&15, row=(lane>>4)*4+j) ---
    float bv[4];
#pragma unroll
    for (int ni = 0; ni < 4; ++ni)
        bv[ni] = bias[bn * BN + wn * 64 + ni * 16 + row16];

    const int rrow = (lane >> 4) * 4;
#pragma unroll
    for (int mi = 0; mi < 4; ++mi) {
#pragma unroll
        for (int ni = 0; ni < 4; ++ni) {
            const int col = bn * BN + wn * 64 + ni * 16 + row16;
#pragma unroll
            for (int j = 0; j < 4; ++j) {
                const int row = bm * BM + wm * 64 + mi * 16 + rrow + j;
                C[(size_t)row * N_DIM + col] = acc[mi][ni][j] + bv[ni];
            }
        }
    }
}

extern "C" void kernel_launch(void* const* d_in, const int* in_sizes, int n_in,
                              void* d_out, int out_size, void* d_ws, size_t ws_size,
                              hipStream_t stream) {
    const float* x        = (const float*)d_in[0];  // 4*2048*2048
    // d_in[1] = router_w  (dead code in reference)
    const float* expert_w = (const float*)d_in[2];  // 8*2048*2048, expert 0 first
    const float* expert_b = (const float*)d_in[3];  // 8*2048, expert 0 first
    float* out = (float*)d_out;

    unsigned short* xb = (unsigned short*)d_ws;                    // 16M bf16
    unsigned short* wb = xb + (size_t)M_DIM * K_DIM;               // 4M bf16

    const int nx4 = (M_DIM * K_DIM) / 4;   // 4,194,304
    const int nw4 = (N_DIM * K_DIM) / 4;   // 1,048,576

    cvt_f32_to_bf16<<<2048, 256, 0, stream>>>(x, expert_w, xb, wb, nx4, nw4);

    dim3 grid((M_DIM / BM) * (N_DIM / BN));  // 64*16 = 1024
    gemm_bt_bias<<<grid, 256, 0, stream>>>(xb, wb, expert_b, out);
}

// Round 3
// 287.239 us; speedup vs baseline: 1.0888x; 1.0888x over previous
//
#include <hip/hip_runtime.h>
#include <hip/hip_bf16.h>
#include <stdint.h>

// out = x @ W0^T + b0 :  C(MxN) = A(MxK)*B(NxK)^T + bias
// M=8192 N=2048 K=2048, fp32 I/O.
// Pass 1: fused fp32->bf16 convert (vectorized 32B load / 16B store).
// Pass 2: 256x256-tile bf16 GEMM, BK=32, 3-buffer LDS ring, 2-tile-ahead
//         global_load_lds prefetch with counted vmcnt(4) (T3/T4), LDS
//         XOR-swizzle (T2), XCD-aware block swizzle (T1), setprio (T5).

#define M_DIM 8192
#define N_DIM 2048
#define K_DIM 2048
#define BM 256
#define BN 256
#define BK 32
#define NT (K_DIM / BK)            // 64 K-tiles
#define BUF_ELEMS 16384            // (A 8192 + B 8192) bf16 per buffer
#define LDS_BYTES (3 * BUF_ELEMS * 2)  // 98304 B

typedef __attribute__((ext_vector_type(8))) short bf16x8;
typedef __attribute__((ext_vector_type(4))) float f32x4;
typedef __attribute__((ext_vector_type(8))) unsigned short u16x8;

__device__ __forceinline__ unsigned short f2bf(float f) {
    union { float f; uint32_t u; } v; v.f = f;
    uint32_t u = v.u;
    uint32_t r = (u + 0x7fffu + ((u >> 16) & 1u)) >> 16;   // RNE
    return (unsigned short)r;
}

// ---------------- Pass 1: convert ----------------
__global__ __launch_bounds__(256) void cvt_f32_to_bf16(
        const float* __restrict__ x, const float* __restrict__ w,
        unsigned short* __restrict__ xb, unsigned short* __restrict__ wb) {
    const int NX8 = (M_DIM * K_DIM) / 8;   // 2,097,152
    const int NW8 = (N_DIM * K_DIM) / 8;   //   524,288
    const int stride = gridDim.x * blockDim.x;
    for (int i = blockIdx.x * blockDim.x + threadIdx.x; i < NX8 + NW8; i += stride) {
        const float4* s; unsigned short* d; int j;
        if (i < NX8) { s = (const float4*)x; d = xb; j = i; }
        else         { s = (const float4*)w; d = wb; j = i - NX8; }
        float4 a = s[2 * j];
        float4 b = s[2 * j + 1];
        u16x8 o;
        o[0] = f2bf(a.x); o[1] = f2bf(a.y); o[2] = f2bf(a.z); o[3] = f2bf(a.w);
        o[4] = f2bf(b.x); o[5] = f2bf(b.y); o[6] = f2bf(b.z); o[7] = f2bf(b.w);
        *(u16x8*)(d + (size_t)8 * j) = o;
    }
}

// ---------------- Pass 2: pipelined GEMM ----------------
// LDS op tile: 256 rows x 32 bf16 (64 B/row) = 16 KB, row-major,
// XOR-swizzled: byte ^= ((byte>>7)&3)<<4  (involution; bits 4-5 <- bits 7-8).
__device__ __forceinline__ int swzE(int row, int colByte) {
    int b = (row << 6) | colByte;
    b ^= ((b >> 7) & 3) << 4;
    return b >> 1;                 // element offset
}

__device__ __forceinline__ void stage_half(const unsigned short* g,
                                           unsigned short* ldsDst) {
    __builtin_amdgcn_global_load_lds(
        (const __attribute__((address_space(1))) void*)g,
        (__attribute__((address_space(3))) void*)ldsDst, 16, 0, 0);
}

__global__ __launch_bounds__(512, 1) void gemm_bt_pipe(
        const unsigned short* __restrict__ A,   // M x K bf16
        const unsigned short* __restrict__ B,   // N x K bf16
        const float* __restrict__ bias,         // N fp32
        float* __restrict__ C) {                // M x N fp32
    extern __shared__ unsigned short lds[];     // 3 ring buffers

    const int tid  = threadIdx.x;
    const int lane = tid & 63;
    const int wv   = tid >> 6;       // 0..7
    const int wm   = wv >> 2;        // 0..1  -> 128-row half
    const int wn   = wv & 3;         // 0..3  -> 64-col quarter

    // T1: XCD-aware bijective block swizzle (256 blocks, 8 XCDs).
    const int bid = blockIdx.x;
    const int lb  = (bid & 7) * 32 + (bid >> 3);
    const int bm0 = (lb & 31) * BM;  // 0..31
    const int bn0 = (lb >> 5) * BN;  // 0..7

    const unsigned short* Ag = A + (size_t)bm0 * K_DIM;
    const unsigned short* Bg = B + (size_t)bn0 * K_DIM;

    // ---- staging addresses (per lane, loop-invariant except k) ----
    // linear LDS byte within 16KB op tile = half*8192 + wv*1024 + lane*16
    const int lin0 = wv * 1024 + lane * 16;
    const int lin1 = 8192 + lin0;
    const int s0 = lin0 ^ (((lin0 >> 7) & 3) << 4);   // inverse-swizzled source
    const int s1 = lin1 ^ (((lin1 >> 7) & 3) << 4);
    const size_t gofs0 = (size_t)(s0 >> 6) * K_DIM + ((s0 & 63) >> 1);
    const size_t gofs1 = (size_t)(s1 >> 6) * K_DIM + ((s1 & 63) >> 1);
    const int dst0 = (wv * 1024) >> 1;                // wave-uniform LDS elem offs
    const int dst1 = (8192 + wv * 1024) >> 1;

    // ---- fragment LDS offsets (loop-invariant) ----
    const int r16  = lane & 15;
    const int c16b = (lane >> 4) << 4;   // 0,16,32,48 bytes (k-group)
    int offA[8], offB[4];
#pragma unroll
    for (int mi = 0; mi < 8; ++mi)
        offA[mi] = swzE(wm * 128 + mi * 16 + r16, c16b);
#pragma unroll
    for (int ni = 0; ni < 4; ++ni)
        offB[ni] = 8192 + swzE(wn * 64 + ni * 16 + r16, c16b);

    f32x4 acc[8][4];
#pragma unroll
    for (int i = 0; i < 8; ++i)
#pragma unroll
        for (int j = 0; j < 4; ++j)
            acc[i][j] = (f32x4){0.f, 0.f, 0.f, 0.f};

    // ---- prologue: stage tiles 0 (buf0) and 1 (buf1): 8 loads/thread ----
#pragma unroll
    for (int tt = 0; tt < 2; ++tt) {
        unsigned short* sA = lds + tt * BUF_ELEMS;
        unsigned short* sB = sA + 8192;
        const int k0 = tt * BK;
        stage_half(Ag + gofs0 + k0, sA + dst0);
        stage_half(Ag + gofs1 + k0, sA + dst1);
        stage_half(Bg + gofs0 + k0, sB + dst0);
        stage_half(Bg + gofs1 + k0, sB + dst1);
    }
    asm volatile("s_waitcnt vmcnt(4)" ::: "memory");   // tile 0 landed, tile 1 in flight
    __builtin_amdgcn_s_barrier();
    asm volatile("" ::: "memory");

    int cb = 0, sb = 2;   // compute buffer, stage buffer (ring of 3)
    for (int t = 0; t < NT; ++t) {
        unsigned short* cbuf = lds + cb * BUF_ELEMS;
        unsigned short* sA   = lds + sb * BUF_ELEMS;
        unsigned short* sB   = sA + 8192;
        const int k2 = (t + 2) * BK;
        const bool doS = (t + 2) < NT;      // block-uniform

        bf16x8 bfr[4];
#pragma unroll
        for (int ni = 0; ni < 4; ++ni)
            bfr[ni] = *(const bf16x8*)(cbuf + offB[ni]);

        // 4 phases: {stage 1 half-tile of t+2} || {2 A-frag ds_reads + 8 MFMA}
#pragma unroll
        for (int ph = 0; ph < 4; ++ph) {
            if (doS) {
                if      (ph == 0) stage_half(Ag + gofs0 + k2, sA + dst0);
                else if (ph == 1) stage_half(Ag + gofs1 + k2, sA + dst1);
                else if (ph == 2) stage_half(Bg + gofs0 + k2, sB + dst0);
                else              stage_half(Bg + gofs1 + k2, sB + dst1);
            }
            bf16x8 a0 = *(const bf16x8*)(cbuf + offA[2 * ph]);
            bf16x8 a1 = *(const bf16x8*)(cbuf + offA[2 * ph + 1]);
            __builtin_amdgcn_s_setprio(1);
#pragma unroll
            for (int ni = 0; ni < 4; ++ni)
                acc[2 * ph][ni] = __builtin_amdgcn_mfma_f32_16x16x32_bf16(
                    a0, bfr[ni], acc[2 * ph][ni], 0, 0, 0);
#pragma unroll
            for (int ni = 0; ni < 4; ++ni)
                acc[2 * ph + 1][ni] = __builtin_amdgcn_mfma_f32_16x16x32_bf16(
                    a1, bfr[ni], acc[2 * ph + 1][ni], 0, 0, 0);
            __builtin_amdgcn_s_setprio(0);
        }

        // Counted drain: allow this tile's 4 prefetch loads to stay in flight;
        // guarantees tile t+1 (issued last tile) has landed. Per-wave counts are
        // identical across the block, so barrier makes it collective.
        if (doS) asm volatile("s_waitcnt vmcnt(4)" ::: "memory");
        else     asm volatile("s_waitcnt vmcnt(0)" ::: "memory");
        __builtin_amdgcn_s_barrier();
        asm volatile("" ::: "memory");

        cb = (cb == 2) ? 0 : cb + 1;
        sb = (sb == 2) ? 0 : sb + 1;
    }

    // ---- epilogue: bias + store (C/D: col=lane&15, row=(lane>>4)*4+j) ----
    float bv[4];
#pragma unroll
    for (int ni = 0; ni < 4; ++ni)
        bv[ni] = bias[bn0 + wn * 64 + ni * 16 + r16];

    const int rrow = (lane >> 4) * 4;
#pragma unroll
    for (int mi = 0; mi < 8; ++mi) {
#pragma unroll
        for (int ni = 0; ni < 4; ++ni) {
            const int col = bn0 + wn * 64 + ni * 16 + r16;
#pragma unroll
            for (int j = 0; j < 4; ++j) {
                const int row = bm0 + wm * 128 + mi * 16 + rrow + j;
                C[(size_t)row * N_DIM + col] = acc[mi][ni][j] + bv[ni];
            }
        }
    }
}

extern "C" void kernel_launch(void* const* d_in, const int* in_sizes, int n_in,
                              void* d_out, int out_size, void* d_ws, size_t ws_size,
                              hipStream_t stream) {
    const float* x        = (const float*)d_in[0];
    const float* expert_w = (const float*)d_in[2];  // expert 0 is first D*D block
    const float* expert_b = (const float*)d_in[3];  // expert 0 is first D block
    float* out = (float*)d_out;

    unsigned short* xb = (unsigned short*)d_ws;                 // 32 MB bf16
    unsigned short* wb = xb + (size_t)M_DIM * K_DIM;            //  8 MB bf16

    cvt_f32_to_bf16<<<2048, 256, 0, stream>>>(x, expert_w, xb, wb);

    (void)hipFuncSetAttribute((const void*)gemm_bt_pipe,
                              hipFuncAttributeMaxDynamicSharedMemorySize,
                              LDS_BYTES);
    gemm_bt_pipe<<<dim3(256), dim3(512), LDS_BYTES, stream>>>(xb, wb, expert_b, out);
}